// Round 1
// baseline (124.717 us; speedup 1.0000x reference)
//
#include <hip/hip_runtime.h>

#define N_FEAT 1024
#define N_LAYER 4

// One 64-lane wave per row. Each lane owns 16 elements of the row as 4x float4
// (lane l, chunk c -> elements c*256 + l*4 .. +3) -> fully coalesced 16B/lane.
// Per layer: per-lane partial dot -> 6-step shfl_xor wave reduction -> fused
// update xi = x0*s + b + xi, all in registers. x read once, out written once.
__global__ __launch_bounds__(256) void crossnet_kernel(
    const float* __restrict__ x,
    const float* __restrict__ weight_w,
    const float* __restrict__ weight_b,
    float* __restrict__ out,
    int n_rows) {
  const int wave = threadIdx.x >> 6;   // 0..3
  const int lane = threadIdx.x & 63;
  const int row = blockIdx.x * 4 + wave;
  if (row >= n_rows) return;

  const float4* xrow = (const float4*)(x + (size_t)row * N_FEAT);
  float4* orow = (float4*)(out + (size_t)row * N_FEAT);

  float4 x0[4], xi[4];
#pragma unroll
  for (int c = 0; c < 4; ++c) {
    x0[c] = xrow[c * 64 + lane];
    xi[c] = x0[c];
  }

#pragma unroll
  for (int l = 0; l < N_LAYER; ++l) {
    const float4* wrow = (const float4*)(weight_w + l * N_FEAT);
    const float4* brow = (const float4*)(weight_b + l * N_FEAT);

    float partial = 0.0f;
#pragma unroll
    for (int c = 0; c < 4; ++c) {
      float4 w = wrow[c * 64 + lane];
      partial += xi[c].x * w.x;
      partial += xi[c].y * w.y;
      partial += xi[c].z * w.z;
      partial += xi[c].w * w.w;
    }
    // 64-lane butterfly reduction (wave = 64 on CDNA)
#pragma unroll
    for (int off = 32; off > 0; off >>= 1)
      partial += __shfl_xor(partial, off, 64);

#pragma unroll
    for (int c = 0; c < 4; ++c) {
      float4 b = brow[c * 64 + lane];
      xi[c].x = fmaf(x0[c].x, partial, b.x + xi[c].x);
      xi[c].y = fmaf(x0[c].y, partial, b.y + xi[c].y);
      xi[c].z = fmaf(x0[c].z, partial, b.z + xi[c].z);
      xi[c].w = fmaf(x0[c].w, partial, b.w + xi[c].w);
    }
  }

#pragma unroll
  for (int c = 0; c < 4; ++c)
    orow[c * 64 + lane] = xi[c];
}

extern "C" void kernel_launch(void* const* d_in, const int* in_sizes, int n_in,
                              void* d_out, int out_size, void* d_ws, size_t ws_size,
                              hipStream_t stream) {
  const float* x = (const float*)d_in[0];
  const float* ww = (const float*)d_in[1];
  const float* wb = (const float*)d_in[2];
  float* out = (float*)d_out;

  int n_rows = in_sizes[0] / N_FEAT;          // 16384
  int n_blocks = (n_rows + 3) / 4;            // 4 rows (waves) per 256-thread block
  crossnet_kernel<<<n_blocks, 256, 0, stream>>>(x, ww, wb, out, n_rows);
}